// Round 6
// baseline (223.580 us; speedup 1.0000x reference)
//
#include <hip/hip_runtime.h>
#include <hip/hip_bf16.h>

#define S_LEN 4096
#define HID   768
#define NH    12
#define HD    64

typedef __attribute__((ext_vector_type(8))) __bf16 bf16x8;
typedef __attribute__((ext_vector_type(4))) float  f32x4;

// round-to-nearest-even fp32 -> bf16
__device__ __forceinline__ unsigned short f2bf(float f) {
  union { float f; unsigned u; } v; v.f = f;
  unsigned r = v.u + 0x7fffu + ((v.u >> 16) & 1u);
  return (unsigned short)(r >> 16);
}

// pack two fp32 -> bf16x2 (low = first arg)
__device__ __forceinline__ unsigned pk2bf(float lo, float hi) {
  __hip_bfloat162 h = __float22bfloat162_rn(make_float2(lo, hi));
  union { __hip_bfloat162 h; unsigned u; } v; v.h = h;
  return v.u;
}

// ---------------------------------------------------------------------------
// Prep 1: X fp32 -> bf16
// ---------------------------------------------------------------------------
__global__ __launch_bounds__(256) void conv_x(const float* __restrict__ X,
                                              unsigned short* __restrict__ Xb)
{
  const int i = blockIdx.x * 256 + threadIdx.x;
  const float4 v = ((const float4*)X)[i];
  ushort4 o;
  o.x = f2bf(v.x); o.y = f2bf(v.y); o.z = f2bf(v.z); o.w = f2bf(v.w);
  ((ushort4*)Xb)[i] = o;
}

// ---------------------------------------------------------------------------
// Prep 2: W [k][n] fp32 -> Wt [n][k] bf16 (z = q/k/v)
// ---------------------------------------------------------------------------
__global__ __launch_bounds__(256) void conv_wt(
    const float* __restrict__ Wq, const float* __restrict__ Wk, const float* __restrict__ Wv,
    unsigned short* __restrict__ Wt)
{
  const int z = blockIdx.z;
  const float* W = (z == 0) ? Wq : (z == 1) ? Wk : Wv;
  unsigned short* O = Wt + (size_t)z * HID * HID;
  const int k0 = blockIdx.x * 64, n0 = blockIdx.y * 64;
  __shared__ unsigned short T[64][72];
  const int tid = threadIdx.x;
  #pragma unroll
  for (int i = tid; i < 512; i += 256) {
    const int kr = i >> 3, c8 = (i & 7) * 8;
    const float4 a = *(const float4*)&W[(size_t)(k0 + kr) * HID + n0 + c8];
    const float4 b = *(const float4*)&W[(size_t)(k0 + kr) * HID + n0 + c8 + 4];
    T[kr][c8 + 0] = f2bf(a.x); T[kr][c8 + 1] = f2bf(a.y);
    T[kr][c8 + 2] = f2bf(a.z); T[kr][c8 + 3] = f2bf(a.w);
    T[kr][c8 + 4] = f2bf(b.x); T[kr][c8 + 5] = f2bf(b.y);
    T[kr][c8 + 6] = f2bf(b.z); T[kr][c8 + 7] = f2bf(b.w);
  }
  __syncthreads();
  #pragma unroll
  for (int i = tid; i < 512; i += 256) {
    const int nr = i >> 3, c8 = (i & 7) * 8;
    ushort4 lo, hi;
    lo.x = T[c8 + 0][nr]; lo.y = T[c8 + 1][nr]; lo.z = T[c8 + 2][nr]; lo.w = T[c8 + 3][nr];
    hi.x = T[c8 + 4][nr]; hi.y = T[c8 + 5][nr]; hi.z = T[c8 + 6][nr]; hi.w = T[c8 + 7][nr];
    ushort4* dst = (ushort4*)&O[(size_t)(n0 + nr) * HID + k0 + c8];
    dst[0] = lo; dst[1] = hi;
  }
}

// ---------------------------------------------------------------------------
// Kernel 1: QKV projection, split-z (grid 12x64x3 = 2304 WGs = 9/CU).
// 64x64 tile, BK=64, register prefetch with pointer-increment addressing,
// XOR-swizzled 16 KB LDS (0 conflicts), LDS-restaged coalesced epilogue.
// Q pre-scaled by 0.125*log2(e). V written [h][d][s] with within-64-block
// permutation tau(s) = (s>>5)*32 + (s&15)*2 + ((s>>4)&1) (= attn's P layout).
// ---------------------------------------------------------------------------
__global__ __launch_bounds__(256) void qkv_proj(
    const unsigned short* __restrict__ Xb, const unsigned short* __restrict__ Wt,
    const float* __restrict__ bq, const float* __restrict__ bk, const float* __restrict__ bv,
    unsigned short* __restrict__ Qo, unsigned short* __restrict__ Ko, unsigned short* __restrict__ Vo)
{
  const int z = blockIdx.z;
  const unsigned short* W = Wt + (size_t)z * HID * HID;   // [n][k]
  const float* bias = (z == 0) ? bq : (z == 1) ? bk : bv;
  unsigned short* Out = (z == 0) ? Qo : (z == 1) ? Ko : Vo;

  const int tid  = threadIdx.x;
  const int wave = tid >> 6;
  const int lane = tid & 63;
  const int g = lane >> 4, c = lane & 15;
  const int h  = blockIdx.x;          // head == n-tile
  const int n0 = h * 64;
  const int m0 = blockIdx.y * 64;

  __shared__ unsigned short Xl[4096];   // [m][k] swizzled
  __shared__ unsigned short Wl[4096];   // [n][k] swizzled

  // staging addresses (loop-invariant LDS offsets; global ptrs advance by 64)
  const int r0 = tid >> 3, c80 = (tid & 7) * 8;
  const unsigned wOff0 = r0 * 64 + (c80 ^ ((r0 & 7) * 8));
  const unsigned wOff1 = (r0 + 32) * 64 + (c80 ^ ((r0 & 7) * 8));   // (r0+32)&7 == r0&7
  const unsigned short* xS0 = &Xb[(size_t)(m0 + r0) * HID + c80];
  const unsigned short* xS1 = &Xb[(size_t)(m0 + r0 + 32) * HID + c80];
  const unsigned short* wS0 = &W[(size_t)(n0 + r0) * HID + c80];
  const unsigned short* wS1 = &W[(size_t)(n0 + r0 + 32) * HID + c80];

  bf16x8 rx0 = *(const bf16x8*)xS0, rx1 = *(const bf16x8*)xS1;
  bf16x8 rw0 = *(const bf16x8*)wS0, rw1 = *(const bf16x8*)wS1;

  // hoisted fragment-read indices
  const int swz = (c & 7) * 8;
  unsigned aRi[2], bRi[8];
  aRi[0] = (wave * 16 + c) * 64 + ((g * 8) ^ swz);
  aRi[1] = (wave * 16 + c) * 64 + ((32 + g * 8) ^ swz);
  #pragma unroll
  for (int nt = 0; nt < 4; ++nt) {
    bRi[2 * nt]     = (nt * 16 + c) * 64 + ((g * 8) ^ swz);
    bRi[2 * nt + 1] = (nt * 16 + c) * 64 + ((32 + g * 8) ^ swz);
  }

  f32x4 acc[4] = {{0.f,0.f,0.f,0.f},{0.f,0.f,0.f,0.f},{0.f,0.f,0.f,0.f},{0.f,0.f,0.f,0.f}};

  for (int k0 = 0; k0 < HID; k0 += 64) {
    __syncthreads();
    *(bf16x8*)&Xl[wOff0] = rx0;
    *(bf16x8*)&Xl[wOff1] = rx1;
    *(bf16x8*)&Wl[wOff0] = rw0;
    *(bf16x8*)&Wl[wOff1] = rw1;
    __syncthreads();

    if (k0 + 64 < HID) {   // prefetch next k-slab (lands during MFMAs)
      xS0 += 64; xS1 += 64; wS0 += 64; wS1 += 64;
      rx0 = *(const bf16x8*)xS0; rx1 = *(const bf16x8*)xS1;
      rw0 = *(const bf16x8*)wS0; rw1 = *(const bf16x8*)wS1;
    }

    const bf16x8 a0 = *(const bf16x8*)&Xl[aRi[0]];
    const bf16x8 a1 = *(const bf16x8*)&Xl[aRi[1]];
    #pragma unroll
    for (int nt = 0; nt < 4; ++nt) {
      const bf16x8 b0 = *(const bf16x8*)&Wl[bRi[2 * nt]];
      const bf16x8 b1 = *(const bf16x8*)&Wl[bRi[2 * nt + 1]];
      acc[nt] = __builtin_amdgcn_mfma_f32_16x16x32_bf16(a0, b0, acc[nt], 0, 0, 0);
      acc[nt] = __builtin_amdgcn_mfma_f32_16x16x32_bf16(a1, b1, acc[nt], 0, 0, 0);
    }
  }

  // epilogue: restage through Xl (swizzled) -> coalesced b128 stores
  const float qsc = (z == 0) ? 0.1803368782f : 1.0f;   // 0.125 * log2(e)
  __syncthreads();
  #pragma unroll
  for (int nt = 0; nt < 4; ++nt) {
    const float bv_ = bias[n0 + nt * 16 + c];
    #pragma unroll
    for (int r = 0; r < 4; ++r) {
      const unsigned short val = f2bf((acc[nt][r] + bv_) * qsc);
      if (z == 2) {
        const int row = nt * 16 + c;                               // d
        const int col = (wave >> 1) * 32 + (4 * g + r) * 2 + (wave & 1);  // tau(s_local)
        Xl[row * 64 + (col ^ ((row & 7) * 8))] = val;
      } else {
        const int row = wave * 16 + 4 * g + r;                     // s_local
        const int col = nt * 16 + c;                               // d
        Xl[row * 64 + (col ^ ((row & 7) * 8))] = val;
      }
    }
  }
  __syncthreads();
  #pragma unroll
  for (int jj = 0; jj < 2; ++jj) {
    const int j = tid + 256 * jj, row = j >> 3, c8 = (j & 7) * 8;
    const bf16x8 v = *(const bf16x8*)&Xl[row * 64 + (c8 ^ ((row & 7) * 8))];
    if (z == 2)
      *(bf16x8*)&Out[((size_t)h * HD + row) * S_LEN + m0 + c8] = v;   // [h][d][s-perm]
    else
      *(bf16x8*)&Out[((size_t)h * S_LEN + m0 + row) * HD + c8] = v;   // [h][s][d]
  }
}

// ---------------------------------------------------------------------------
// Kernel 2: attention. 4 waves x 32 q = 128 q/WG, KV-split 4 -> 1536 WGs
// (5 resident/CU by 32 KB LDS). Swizzled LDS (0 conflicts), exp2 no-max
// softmax (Q pre-scaled by log2e/8, raw v_exp_f32), packed b32 P stores with
// tau permutation (matched by V layout), K/V register prefetch with
// pointer-increment addressing, hoisted LDS indices. Denominator via
// ones-column MFMA; partials atomicAdd'ed (4 contributions per element).
// ---------------------------------------------------------------------------
__global__ __launch_bounds__(256) void attn(
    const unsigned short* __restrict__ Q, const unsigned short* __restrict__ K,
    const unsigned short* __restrict__ Vp,   // [h][d][s-perm]
    float* __restrict__ O, float* __restrict__ L)
{
  const int qt = blockIdx.x;   // 0..31
  const int h  = blockIdx.y;   // 0..11
  const int sp = blockIdx.z;   // 0..3
  const int tid  = threadIdx.x;
  const int wave = tid >> 6;
  const int lane = tid & 63;
  const int g = lane >> 4, c = lane & 15;
  const int q0 = qt * 128;
  const int k_base = sp * 1024;

  __shared__ unsigned short Kl[4096];      // [key][d] swizzled
  __shared__ unsigned short Vt[4096];      // [d][key-perm] swizzled
  __shared__ unsigned short Pl[4][2048];   // per-wave P [32 q][64 key-perm] swizzled
  unsigned short* PlFlat = &Pl[0][0];      // doubles as Q staging [128][64]

  const int swz = (c & 7) * 8;

  // stage Q tile (128x64 = 16 KB) into the P region, swizzled
  #pragma unroll
  for (int i = tid; i < 1024; i += 256) {
    const int row = i >> 3, c8 = (i & 7) * 8;
    *(bf16x8*)&PlFlat[row * 64 + (c8 ^ ((row & 7) * 8))] =
        *(const bf16x8*)&Q[((size_t)h * S_LEN + q0 + row) * HD + c8];
  }
  __syncthreads();

  // Q A-frags (protected from P overwrite by the two barriers of iter 0)
  bf16x8 aq[2][2];
  #pragma unroll
  for (int s = 0; s < 2; ++s) {
    const int row = wave * 32 + s * 16 + c;
    aq[s][0] = *(const bf16x8*)&PlFlat[row * 64 + ((g * 8) ^ swz)];
    aq[s][1] = *(const bf16x8*)&PlFlat[row * 64 + ((32 + g * 8) ^ swz)];
  }

  bf16x8 bones;   // B column 0 = 1.0 -> C[:,0] = row sums
  {
    const unsigned short one_bf = (c == 0) ? 0x3F80u : 0u;
    #pragma unroll
    for (int j = 0; j < 8; ++j) ((unsigned short*)&bones)[j] = one_bf;
  }

  // hoisted LDS fragment indices
  unsigned kRi[8], vRi[8], pRi[4], pW[2][4];
  #pragma unroll
  for (int nt = 0; nt < 4; ++nt) {
    kRi[2 * nt]     = (nt * 16 + c) * 64 + ((g * 8) ^ swz);
    kRi[2 * nt + 1] = (nt * 16 + c) * 64 + ((32 + g * 8) ^ swz);
    vRi[2 * nt]     = kRi[2 * nt];
    vRi[2 * nt + 1] = kRi[2 * nt + 1];
  }
  #pragma unroll
  for (int s = 0; s < 2; ++s) {
    pRi[2 * s]     = (s * 16 + c) * 64 + ((g * 8) ^ swz);
    pRi[2 * s + 1] = (s * 16 + c) * 64 + ((32 + g * 8) ^ swz);
    #pragma unroll
    for (int r = 0; r < 4; ++r) {
      const int row = s * 16 + 4 * g + r;
      pW[s][r] = row * 64 + ((2 * c) ^ ((row & 7) * 8));   // pr=1: index ^ 32
    }
  }

  // staging addresses: LDS offsets invariant, global ptrs incremented
  const int r0 = tid >> 3, c80 = (tid & 7) * 8;
  const unsigned wOff0 = r0 * 64 + (c80 ^ ((r0 & 7) * 8));
  const unsigned wOff1 = (r0 + 32) * 64 + (c80 ^ ((r0 & 7) * 8));
  const unsigned short* kS0 = &K[((size_t)h * S_LEN + k_base + r0) * HD + c80];
  const unsigned short* kS1 = kS0 + (size_t)32 * HD;
  const unsigned short* vS0 = &Vp[((size_t)h * HD + r0) * S_LEN + k_base + c80];
  const unsigned short* vS1 = vS0 + (size_t)32 * S_LEN;

  bf16x8 rk0 = *(const bf16x8*)kS0, rk1 = *(const bf16x8*)kS1;
  bf16x8 rv0 = *(const bf16x8*)vS0, rv1 = *(const bf16x8*)vS1;

  f32x4 o[2][4];
  #pragma unroll
  for (int s = 0; s < 2; ++s)
    #pragma unroll
    for (int nt = 0; nt < 4; ++nt) o[s][nt] = (f32x4){0.f, 0.f, 0.f, 0.f};
  f32x4 lacc[2] = {{0.f,0.f,0.f,0.f},{0.f,0.f,0.f,0.f}};

  unsigned short* P = Pl[wave];

  for (int kt = 0; kt < 16; ++kt) {
    __syncthreads();   // prev frag reads + (first iter) Q-frag reads done
    *(bf16x8*)&Kl[wOff0] = rk0;
    *(bf16x8*)&Kl[wOff1] = rk1;
    *(bf16x8*)&Vt[wOff0] = rv0;
    *(bf16x8*)&Vt[wOff1] = rv1;
    __syncthreads();

    if (kt + 1 < 16) {   // prefetch next tile; lands during compute below
      kS0 += (size_t)64 * HD; kS1 += (size_t)64 * HD; vS0 += 64; vS1 += 64;
      rk0 = *(const bf16x8*)kS0; rk1 = *(const bf16x8*)kS1;
      rv0 = *(const bf16x8*)vS0; rv1 = *(const bf16x8*)vS1;
    }

    // QK^T in nt-pairs; exp2 + b32 packed P stores
    #pragma unroll
    for (int pr = 0; pr < 2; ++pr) {
      f32x4 sc[2][2];
      #pragma unroll
      for (int ntl = 0; ntl < 2; ++ntl) {
        const int nt = pr * 2 + ntl;
        const bf16x8 b0 = *(const bf16x8*)&Kl[kRi[2 * nt]];
        const bf16x8 b1 = *(const bf16x8*)&Kl[kRi[2 * nt + 1]];
        #pragma unroll
        for (int s = 0; s < 2; ++s) {
          f32x4 z = {0.f, 0.f, 0.f, 0.f};
          z = __builtin_amdgcn_mfma_f32_16x16x32_bf16(aq[s][0], b0, z, 0, 0, 0);
          z = __builtin_amdgcn_mfma_f32_16x16x32_bf16(aq[s][1], b1, z, 0, 0, 0);
          sc[ntl][s] = z;
        }
      }
      #pragma unroll
      for (int s = 0; s < 2; ++s) {
        #pragma unroll
        for (int r = 0; r < 4; ++r) {
          const unsigned u = pk2bf(__builtin_amdgcn_exp2f(sc[0][s][r]),
                                   __builtin_amdgcn_exp2f(sc[1][s][r]));
          *(unsigned*)&P[pW[s][r] ^ (pr * 32)] = u;
        }
      }
    }

    // O += P V ; lacc += P @ ones  (same-wave write->read; lgkmcnt by compiler)
    bf16x8 ap[2][2];
    #pragma unroll
    for (int s = 0; s < 2; ++s) {
      ap[s][0] = *(const bf16x8*)&P[pRi[2 * s]];
      ap[s][1] = *(const bf16x8*)&P[pRi[2 * s + 1]];
    }
    #pragma unroll
    for (int nt = 0; nt < 4; ++nt) {
      const bf16x8 b0 = *(const bf16x8*)&Vt[vRi[2 * nt]];
      const bf16x8 b1 = *(const bf16x8*)&Vt[vRi[2 * nt + 1]];
      #pragma unroll
      for (int s = 0; s < 2; ++s) {
        o[s][nt] = __builtin_amdgcn_mfma_f32_16x16x32_bf16(ap[s][0], b0, o[s][nt], 0, 0, 0);
        o[s][nt] = __builtin_amdgcn_mfma_f32_16x16x32_bf16(ap[s][1], b1, o[s][nt], 0, 0, 0);
      }
    }
    #pragma unroll
    for (int s = 0; s < 2; ++s) {
      lacc[s] = __builtin_amdgcn_mfma_f32_16x16x32_bf16(ap[s][0], bones, lacc[s], 0, 0, 0);
      lacc[s] = __builtin_amdgcn_mfma_f32_16x16x32_bf16(ap[s][1], bones, lacc[s], 0, 0, 0);
    }
  }

  // epilogue: accumulate partials (exactly 4 contributions per element)
  #pragma unroll
  for (int s = 0; s < 2; ++s) {
    #pragma unroll
    for (int nt = 0; nt < 4; ++nt) {
      #pragma unroll
      for (int r = 0; r < 4; ++r) {
        const int row = q0 + wave * 32 + s * 16 + 4 * g + r;
        atomicAdd(&O[(size_t)row * HID + h * HD + nt * 16 + c], o[s][nt][r]);
      }
    }
  }
  if (c == 0) {
    #pragma unroll
    for (int s = 0; s < 2; ++s)
      #pragma unroll
      for (int r = 0; r < 4; ++r)
        atomicAdd(&L[h * S_LEN + q0 + wave * 32 + s * 16 + 4 * g + r], lacc[s][r]);
  }
}

// ---------------------------------------------------------------------------
// Kernel 3: normalize O by softmax denominator
// ---------------------------------------------------------------------------
__global__ __launch_bounds__(256) void normalize(float* __restrict__ O,
                                                 const float* __restrict__ L)
{
  const int i = blockIdx.x * 256 + threadIdx.x;
  float4 v = ((const float4*)O)[i];
  const int idx4 = i * 4;
  const int row = idx4 / HID;
  const int h   = (idx4 % HID) >> 6;
  const float inv = 1.0f / L[h * S_LEN + row];
  v.x *= inv; v.y *= inv; v.z *= inv; v.w *= inv;
  ((float4*)O)[i] = v;
}

// ---------------------------------------------------------------------------
extern "C" void kernel_launch(void* const* d_in, const int* in_sizes, int n_in,
                              void* d_out, int out_size, void* d_ws, size_t ws_size,
                              hipStream_t stream) {
  const float* X  = (const float*)d_in[0];
  const float* Wq = (const float*)d_in[1];
  const float* bq = (const float*)d_in[2];
  const float* Wk = (const float*)d_in[3];
  const float* bk = (const float*)d_in[4];
  const float* Wv = (const float*)d_in[5];
  const float* bv = (const float*)d_in[6];

  unsigned short* Xb = (unsigned short*)d_ws;
  unsigned short* Wt = Xb + (size_t)S_LEN * HID;
  unsigned short* Qb = Wt + (size_t)3 * HID * HID;
  unsigned short* Kb = Qb + (size_t)NH * S_LEN * HD;
  unsigned short* Vb = Kb + (size_t)NH * S_LEN * HD;
  float* L = (float*)(Vb + (size_t)NH * S_LEN * HD);
  float* O = (float*)d_out;

  hipMemsetAsync(O, 0, (size_t)S_LEN * HID * sizeof(float), stream);
  hipMemsetAsync(L, 0, (size_t)NH * S_LEN * sizeof(float), stream);

  conv_x <<<dim3((S_LEN * HID / 4) / 256), 256, 0, stream>>>(X, Xb);
  conv_wt<<<dim3(12, 12, 3), 256, 0, stream>>>(Wq, Wk, Wv, Wt);
  qkv_proj<<<dim3(12, 64, 3), 256, 0, stream>>>(Xb, Wt, bq, bk, bv, Qb, Kb, Vb);
  attn<<<dim3(32, 12, 4), 256, 0, stream>>>(Qb, Kb, Vb, O, L);
  normalize<<<dim3((S_LEN * HID / 4) / 256), 256, 0, stream>>>(O, L);
}

// Round 7
// 211.138 us; speedup vs baseline: 1.0589x; 1.0589x over previous
//
#include <hip/hip_runtime.h>
#include <hip/hip_bf16.h>

#define S_LEN 4096
#define HID   768
#define NH    12
#define HD    64

typedef __attribute__((ext_vector_type(8))) __bf16 bf16x8;
typedef __attribute__((ext_vector_type(4))) float  f32x4;
typedef __attribute__((ext_vector_type(4))) short  s16x4;   // 4 bf16 for 16x16x16 MFMA

// 16x16x16 bf16 MFMA (A: lane{g,c} holds A[m=c][k=4g+j]; C: lane reg r = C[4g+r][c])
#if __has_builtin(__builtin_amdgcn_mfma_f32_16x16x16bf16_1k)
__device__ __forceinline__ f32x4 mfma16(s16x4 a, s16x4 b, f32x4 c) {
  return __builtin_amdgcn_mfma_f32_16x16x16bf16_1k(a, b, c, 0, 0, 0);
}
#else
__device__ __forceinline__ f32x4 mfma16(s16x4 a, s16x4 b, f32x4 c) {
  f32x4 d;
  asm volatile("v_mfma_f32_16x16x16_bf16 %0, %1, %2, %3"
               : "=&v"(d) : "v"(a), "v"(b), "v"(c));
  return d;
}
#endif

// round-to-nearest-even fp32 -> bf16
__device__ __forceinline__ unsigned short f2bf(float f) {
  union { float f; unsigned u; } v; v.f = f;
  unsigned r = v.u + 0x7fffu + ((v.u >> 16) & 1u);
  return (unsigned short)(r >> 16);
}

// pack two fp32 -> bf16x2 (low = first arg)
__device__ __forceinline__ unsigned pk2bf(float lo, float hi) {
  __hip_bfloat162 h = __float22bfloat162_rn(make_float2(lo, hi));
  union { __hip_bfloat162 h; unsigned u; } v; v.h = h;
  return v.u;
}

// ---------------------------------------------------------------------------
// Prep (single launch): X->bf16 | W->Wt bf16 transposed | zero O | zero L
// blocks [0,3072): conv_x ; [3072,3504): conv_wt ; [3504,6576): zero O ;
// [6576,6624): zero L
// ---------------------------------------------------------------------------
__global__ __launch_bounds__(256) void prep(
    const float* __restrict__ X,
    const float* __restrict__ Wq, const float* __restrict__ Wk, const float* __restrict__ Wv,
    unsigned short* __restrict__ Xb, unsigned short* __restrict__ Wt,
    float* __restrict__ O, float* __restrict__ L)
{
  const int b = blockIdx.x, tid = threadIdx.x;
  __shared__ unsigned short T[64][72];

  if (b < 3072) {                      // X fp32 -> bf16
    const int i = b * 256 + tid;
    const float4 v = ((const float4*)X)[i];
    ushort4 o;
    o.x = f2bf(v.x); o.y = f2bf(v.y); o.z = f2bf(v.z); o.w = f2bf(v.w);
    ((ushort4*)Xb)[i] = o;
  } else if (b < 3504) {               // W [k][n] -> Wt [n][k] bf16, 64x64 tiles
    const int t = b - 3072;
    const int z = t / 144, rem = t % 144;
    const int k0 = (rem / 12) * 64, n0 = (rem % 12) * 64;
    const float* W = (z == 0) ? Wq : (z == 1) ? Wk : Wv;
    unsigned short* Od = Wt + (size_t)z * HID * HID;
    #pragma unroll
    for (int i = tid; i < 512; i += 256) {
      const int kr = i >> 3, c8 = (i & 7) * 8;
      const float4 a = *(const float4*)&W[(size_t)(k0 + kr) * HID + n0 + c8];
      const float4 bb = *(const float4*)&W[(size_t)(k0 + kr) * HID + n0 + c8 + 4];
      T[kr][c8 + 0] = f2bf(a.x);  T[kr][c8 + 1] = f2bf(a.y);
      T[kr][c8 + 2] = f2bf(a.z);  T[kr][c8 + 3] = f2bf(a.w);
      T[kr][c8 + 4] = f2bf(bb.x); T[kr][c8 + 5] = f2bf(bb.y);
      T[kr][c8 + 6] = f2bf(bb.z); T[kr][c8 + 7] = f2bf(bb.w);
    }
    __syncthreads();
    #pragma unroll
    for (int i = tid; i < 512; i += 256) {
      const int nr = i >> 3, c8 = (i & 7) * 8;
      ushort4 lo, hi;
      lo.x = T[c8 + 0][nr]; lo.y = T[c8 + 1][nr]; lo.z = T[c8 + 2][nr]; lo.w = T[c8 + 3][nr];
      hi.x = T[c8 + 4][nr]; hi.y = T[c8 + 5][nr]; hi.z = T[c8 + 6][nr]; hi.w = T[c8 + 7][nr];
      ushort4* dst = (ushort4*)&Od[(size_t)(n0 + nr) * HID + k0 + c8];
      dst[0] = lo; dst[1] = hi;
    }
  } else if (b < 6576) {               // zero O
    ((float4*)O)[(b - 3504) * 256 + tid] = (float4){0.f, 0.f, 0.f, 0.f};
  } else {                             // zero L
    ((float4*)L)[(b - 6576) * 256 + tid] = (float4){0.f, 0.f, 0.f, 0.f};
  }
}

// ---------------------------------------------------------------------------
// Kernel 1: QKV projection, split-z (grid 12x64x3 = 2304 WGs).
// 64x64 tile, BK=64, register prefetch, XOR-swizzled LDS, LDS-restaged
// coalesced epilogue. Q pre-scaled by 0.125*log2(e). V written plain
// [h][d][s] (no permutation).
// ---------------------------------------------------------------------------
__global__ __launch_bounds__(256) void qkv_proj(
    const unsigned short* __restrict__ Xb, const unsigned short* __restrict__ Wt,
    const float* __restrict__ bq, const float* __restrict__ bk, const float* __restrict__ bv,
    unsigned short* __restrict__ Qo, unsigned short* __restrict__ Ko, unsigned short* __restrict__ Vo)
{
  const int z = blockIdx.z;
  const unsigned short* W = Wt + (size_t)z * HID * HID;   // [n][k]
  const float* bias = (z == 0) ? bq : (z == 1) ? bk : bv;
  unsigned short* Out = (z == 0) ? Qo : (z == 1) ? Ko : Vo;

  const int tid  = threadIdx.x;
  const int wave = tid >> 6;
  const int lane = tid & 63;
  const int g = lane >> 4, c = lane & 15;
  const int h  = blockIdx.x;
  const int n0 = h * 64;
  const int m0 = blockIdx.y * 64;

  __shared__ unsigned short Xl[4096];   // [m][k] swizzled
  __shared__ unsigned short Wl[4096];   // [n][k] swizzled

  const int r0 = tid >> 3, c80 = (tid & 7) * 8;
  const unsigned wOff0 = r0 * 64 + (c80 ^ ((r0 & 7) * 8));
  const unsigned wOff1 = (r0 + 32) * 64 + (c80 ^ ((r0 & 7) * 8));
  const unsigned short* xS0 = &Xb[(size_t)(m0 + r0) * HID + c80];
  const unsigned short* xS1 = &Xb[(size_t)(m0 + r0 + 32) * HID + c80];
  const unsigned short* wS0 = &W[(size_t)(n0 + r0) * HID + c80];
  const unsigned short* wS1 = &W[(size_t)(n0 + r0 + 32) * HID + c80];

  bf16x8 rx0 = *(const bf16x8*)xS0, rx1 = *(const bf16x8*)xS1;
  bf16x8 rw0 = *(const bf16x8*)wS0, rw1 = *(const bf16x8*)wS1;

  const int swz = (c & 7) * 8;
  unsigned aRi[2], bRi[8];
  aRi[0] = (wave * 16 + c) * 64 + ((g * 8) ^ swz);
  aRi[1] = (wave * 16 + c) * 64 + ((32 + g * 8) ^ swz);
  #pragma unroll
  for (int nt = 0; nt < 4; ++nt) {
    bRi[2 * nt]     = (nt * 16 + c) * 64 + ((g * 8) ^ swz);
    bRi[2 * nt + 1] = (nt * 16 + c) * 64 + ((32 + g * 8) ^ swz);
  }

  f32x4 acc[4] = {{0.f,0.f,0.f,0.f},{0.f,0.f,0.f,0.f},{0.f,0.f,0.f,0.f},{0.f,0.f,0.f,0.f}};

  for (int k0 = 0; k0 < HID; k0 += 64) {
    __syncthreads();
    *(bf16x8*)&Xl[wOff0] = rx0;
    *(bf16x8*)&Xl[wOff1] = rx1;
    *(bf16x8*)&Wl[wOff0] = rw0;
    *(bf16x8*)&Wl[wOff1] = rw1;
    __syncthreads();

    if (k0 + 64 < HID) {
      xS0 += 64; xS1 += 64; wS0 += 64; wS1 += 64;
      rx0 = *(const bf16x8*)xS0; rx1 = *(const bf16x8*)xS1;
      rw0 = *(const bf16x8*)wS0; rw1 = *(const bf16x8*)wS1;
    }

    const bf16x8 a0 = *(const bf16x8*)&Xl[aRi[0]];
    const bf16x8 a1 = *(const bf16x8*)&Xl[aRi[1]];
    #pragma unroll
    for (int nt = 0; nt < 4; ++nt) {
      const bf16x8 b0 = *(const bf16x8*)&Wl[bRi[2 * nt]];
      const bf16x8 b1 = *(const bf16x8*)&Wl[bRi[2 * nt + 1]];
      acc[nt] = __builtin_amdgcn_mfma_f32_16x16x32_bf16(a0, b0, acc[nt], 0, 0, 0);
      acc[nt] = __builtin_amdgcn_mfma_f32_16x16x32_bf16(a1, b1, acc[nt], 0, 0, 0);
    }
  }

  // epilogue: restage through Xl (swizzled) -> coalesced b128 stores
  const float qsc = (z == 0) ? 0.1803368782f : 1.0f;   // 0.125 * log2(e)
  __syncthreads();
  #pragma unroll
  for (int nt = 0; nt < 4; ++nt) {
    const float bv_ = bias[n0 + nt * 16 + c];
    #pragma unroll
    for (int r = 0; r < 4; ++r) {
      const unsigned short val = f2bf((acc[nt][r] + bv_) * qsc);
      if (z == 2) {
        const int row = nt * 16 + c;               // d
        const int col = wave * 16 + 4 * g + r;     // s_local (plain)
        Xl[row * 64 + (col ^ ((row & 7) * 8))] = val;
      } else {
        const int row = wave * 16 + 4 * g + r;     // s_local
        const int col = nt * 16 + c;               // d
        Xl[row * 64 + (col ^ ((row & 7) * 8))] = val;
      }
    }
  }
  __syncthreads();
  #pragma unroll
  for (int jj = 0; jj < 2; ++jj) {
    const int j = tid + 256 * jj, row = j >> 3, c8 = (j & 7) * 8;
    const bf16x8 v = *(const bf16x8*)&Xl[row * 64 + (c8 ^ ((row & 7) * 8))];
    if (z == 2)
      *(bf16x8*)&Out[((size_t)h * HD + row) * S_LEN + m0 + c8] = v;   // [h][d][s]
    else
      *(bf16x8*)&Out[((size_t)h * S_LEN + m0 + row) * HD + c8] = v;   // [h][s][d]
  }
}

// ---------------------------------------------------------------------------
// Kernel 2: attention, S^T formulation — no P LDS round-trip.
// 4 waves x 32 q = 128 q/WG, KV-split 2 -> 768 WGs.
// S^T = K Q^T via 16x16x32 MFMA (C-layout = PV A-layout for 16x16x16 MFMA);
// exp2 + bf16-pack in registers feeds PV (v_mfma_f32_16x16x16_bf16) directly.
// V B-frags: b64 reads from Vt [d][key], row stride 68. Denominator via
// ones-column 16x16x16 MFMA. Partials atomicAdd'ed (2 per element).
// ---------------------------------------------------------------------------
__global__ __launch_bounds__(256) void attn(
    const unsigned short* __restrict__ Q, const unsigned short* __restrict__ K,
    const unsigned short* __restrict__ Vp,   // [h][d][s]
    float* __restrict__ O, float* __restrict__ L)
{
  const int qt = blockIdx.x;   // 0..31
  const int h  = blockIdx.y;   // 0..11
  const int sp = blockIdx.z;   // 0..1
  const int tid  = threadIdx.x;
  const int wave = tid >> 6;
  const int lane = tid & 63;
  const int g = lane >> 4, c = lane & 15;
  const int q0 = qt * 128;
  const int k_base = sp * 2048;

  __shared__ unsigned short Kl[4096];       // [key][d] swizzled, stride 64
  __shared__ unsigned short Vt[64 * 68];    // [d][key], stride 68 (bank spread)

  // Q B-frags straight from global (loop-invariant)
  bf16x8 aq[2][2];
  #pragma unroll
  for (int s = 0; s < 2; ++s) {
    const size_t qrow = (size_t)h * S_LEN + q0 + wave * 32 + s * 16 + c;
    aq[s][0] = *(const bf16x8*)&Q[qrow * HD + g * 8];
    aq[s][1] = *(const bf16x8*)&Q[qrow * HD + 32 + g * 8];
  }

  s16x4 bones;   // B column 0 = 1.0 -> C[:,0] = row sums (16x16x16 B-frag)
  {
    const short one_bf = (c == 0) ? (short)0x3F80 : (short)0;
    bones = (s16x4){one_bf, one_bf, one_bf, one_bf};
  }

  const int swz = (c & 7) * 8;
  unsigned kRi[8];
  #pragma unroll
  for (int mt = 0; mt < 4; ++mt) {
    kRi[2 * mt]     = (mt * 16 + c) * 64 + ((g * 8) ^ swz);
    kRi[2 * mt + 1] = (mt * 16 + c) * 64 + ((32 + g * 8) ^ swz);
  }
  const unsigned vBase = c * 68 + 4 * g;   // + dt*16*68 + mt*16 (imm offsets)

  // staging: LDS offsets invariant; global pointers advance
  const int r0 = tid >> 3, c80 = (tid & 7) * 8;
  const unsigned kOff0 = r0 * 64 + (c80 ^ ((r0 & 7) * 8));
  const unsigned kOff1 = (r0 + 32) * 64 + (c80 ^ ((r0 & 7) * 8));
  const unsigned vOff0 = r0 * 68 + c80;
  const unsigned vOff1 = (r0 + 32) * 68 + c80;
  const unsigned short* kS0 = &K[((size_t)h * S_LEN + k_base + r0) * HD + c80];
  const unsigned short* kS1 = kS0 + (size_t)32 * HD;
  const unsigned short* vS0 = &Vp[((size_t)h * HD + r0) * S_LEN + k_base + c80];
  const unsigned short* vS1 = vS0 + (size_t)32 * S_LEN;

  bf16x8 rk0 = *(const bf16x8*)kS0, rk1 = *(const bf16x8*)kS1;
  bf16x8 rv0 = *(const bf16x8*)vS0, rv1 = *(const bf16x8*)vS1;

  f32x4 o[2][4];
  #pragma unroll
  for (int s = 0; s < 2; ++s)
    #pragma unroll
    for (int dt = 0; dt < 4; ++dt) o[s][dt] = (f32x4){0.f, 0.f, 0.f, 0.f};
  f32x4 lacc[2] = {{0.f,0.f,0.f,0.f},{0.f,0.f,0.f,0.f}};

  for (int kt = 0; kt < 32; ++kt) {
    __syncthreads();
    *(bf16x8*)&Kl[kOff0] = rk0;
    *(bf16x8*)&Kl[kOff1] = rk1;
    *(bf16x8*)&Vt[vOff0] = rv0;
    *(bf16x8*)&Vt[vOff1] = rv1;
    __syncthreads();

    if (kt + 1 < 32) {   // prefetch next tile
      kS0 += 64 * HD; kS1 += 64 * HD; vS0 += 64; vS1 += 64;
      rk0 = *(const bf16x8*)kS0; rk1 = *(const bf16x8*)kS1;
      rv0 = *(const bf16x8*)vS0; rv1 = *(const bf16x8*)vS1;
    }

    // S^T = K Q^T per key-tile mt; exp2 + pack -> PV A-operands (registers only)
    s16x4 ap[2][4];
    #pragma unroll
    for (int mt = 0; mt < 4; ++mt) {
      const bf16x8 kf0 = *(const bf16x8*)&Kl[kRi[2 * mt]];
      const bf16x8 kf1 = *(const bf16x8*)&Kl[kRi[2 * mt + 1]];
      #pragma unroll
      for (int s = 0; s < 2; ++s) {
        f32x4 st = {0.f, 0.f, 0.f, 0.f};
        st = __builtin_amdgcn_mfma_f32_16x16x32_bf16(kf0, aq[s][0], st, 0, 0, 0);
        st = __builtin_amdgcn_mfma_f32_16x16x32_bf16(kf1, aq[s][1], st, 0, 0, 0);
        union { unsigned u[2]; s16x4 v; } pk;
        pk.u[0] = pk2bf(exp2f(st[0]), exp2f(st[1]));
        pk.u[1] = pk2bf(exp2f(st[2]), exp2f(st[3]));
        ap[s][mt] = pk.v;
      }
    }

    // O += P V  (16x16x16 MFMAs; V b64 B-frags from Vt)
    #pragma unroll
    for (int dt = 0; dt < 4; ++dt) {
      s16x4 vb[4];
      #pragma unroll
      for (int mt = 0; mt < 4; ++mt)
        vb[mt] = *(const s16x4*)&Vt[vBase + (unsigned)(dt * 16 * 68 + mt * 16)];
      #pragma unroll
      for (int s = 0; s < 2; ++s) {
        #pragma unroll
        for (int mt = 0; mt < 4; ++mt)
          o[s][dt] = mfma16(ap[s][mt], vb[mt], o[s][dt]);
      }
    }
    // denominator
    #pragma unroll
    for (int s = 0; s < 2; ++s)
      #pragma unroll
      for (int mt = 0; mt < 4; ++mt)
        lacc[s] = mfma16(ap[s][mt], bones, lacc[s]);
  }

  // epilogue: accumulate partials (exactly 2 contributions per element)
  #pragma unroll
  for (int s = 0; s < 2; ++s) {
    #pragma unroll
    for (int dt = 0; dt < 4; ++dt) {
      #pragma unroll
      for (int r = 0; r < 4; ++r) {
        const int row = q0 + wave * 32 + s * 16 + 4 * g + r;
        atomicAdd(&O[(size_t)row * HID + h * HD + dt * 16 + c], o[s][dt][r]);
      }
    }
  }
  if (c == 0) {
    #pragma unroll
    for (int s = 0; s < 2; ++s)
      #pragma unroll
      for (int r = 0; r < 4; ++r)
        atomicAdd(&L[h * S_LEN + q0 + wave * 32 + s * 16 + 4 * g + r], lacc[s][r]);
  }
}

// ---------------------------------------------------------------------------
// Kernel 3: normalize O by softmax denominator
// ---------------------------------------------------------------------------
__global__ __launch_bounds__(256) void normalize(float* __restrict__ O,
                                                 const float* __restrict__ L)
{
  const int i = blockIdx.x * 256 + threadIdx.x;
  float4 v = ((const float4*)O)[i];
  const int idx4 = i * 4;
  const int row = idx4 / HID;
  const int h   = (idx4 % HID) >> 6;
  const float inv = 1.0f / L[h * S_LEN + row];
  v.x *= inv; v.y *= inv; v.z *= inv; v.w *= inv;
  ((float4*)O)[i] = v;
}

// ---------------------------------------------------------------------------
extern "C" void kernel_launch(void* const* d_in, const int* in_sizes, int n_in,
                              void* d_out, int out_size, void* d_ws, size_t ws_size,
                              hipStream_t stream) {
  const float* X  = (const float*)d_in[0];
  const float* Wq = (const float*)d_in[1];
  const float* bq = (const float*)d_in[2];
  const float* Wk = (const float*)d_in[3];
  const float* bk = (const float*)d_in[4];
  const float* Wv = (const float*)d_in[5];
  const float* bv = (const float*)d_in[6];

  unsigned short* Xb = (unsigned short*)d_ws;
  unsigned short* Wt = Xb + (size_t)S_LEN * HID;
  unsigned short* Qb = Wt + (size_t)3 * HID * HID;
  unsigned short* Kb = Qb + (size_t)NH * S_LEN * HD;
  unsigned short* Vb = Kb + (size_t)NH * S_LEN * HD;
  float* L = (float*)(Vb + (size_t)NH * S_LEN * HD);
  float* O = (float*)d_out;

  prep<<<dim3(6624), 256, 0, stream>>>(X, Wq, Wk, Wv, Xb, Wt, O, L);
  qkv_proj<<<dim3(12, 64, 3), 256, 0, stream>>>(Xb, Wt, bq, bk, bv, Qb, Kb, Vb);
  attn<<<dim3(32, 12, 2), 256, 0, stream>>>(Qb, Kb, Vb, O, L);
  normalize<<<dim3((S_LEN * HID / 4) / 256), 256, 0, stream>>>(O, L);
}

// Round 8
// 185.575 us; speedup vs baseline: 1.2048x; 1.1378x over previous
//
#include <hip/hip_runtime.h>
#include <hip/hip_bf16.h>

#define S_LEN 4096
#define HID   768
#define NH    12
#define HD    64

typedef __attribute__((ext_vector_type(8))) __bf16 bf16x8;
typedef __attribute__((ext_vector_type(4))) float  f32x4;

// round-to-nearest-even fp32 -> bf16
__device__ __forceinline__ unsigned short f2bf(float f) {
  union { float f; unsigned u; } v; v.f = f;
  unsigned r = v.u + 0x7fffu + ((v.u >> 16) & 1u);
  return (unsigned short)(r >> 16);
}

// truncating pack of two fp32 into [bf16(hi) | bf16(lo)] — single v_perm_b32.
// Truncation bias cancels in O = (P V)/(P 1) since denominator uses same P.
__device__ __forceinline__ unsigned pktr(float lo, float hi) {
  union { float f; unsigned u; } a, b; a.f = lo; b.f = hi;
  return __builtin_amdgcn_perm(b.u, a.u, 0x07060302u);
}

// ---------------------------------------------------------------------------
// Prep (single launch): X->bf16 | W->Wt bf16 transposed | zero O | zero L
// ---------------------------------------------------------------------------
__global__ __launch_bounds__(256) void prep(
    const float* __restrict__ X,
    const float* __restrict__ Wq, const float* __restrict__ Wk, const float* __restrict__ Wv,
    unsigned short* __restrict__ Xb, unsigned short* __restrict__ Wt,
    float* __restrict__ O, float* __restrict__ L)
{
  const int b = blockIdx.x, tid = threadIdx.x;
  __shared__ unsigned short T[64][72];

  if (b < 3072) {                      // X fp32 -> bf16
    const int i = b * 256 + tid;
    const float4 v = ((const float4*)X)[i];
    ushort4 o;
    o.x = f2bf(v.x); o.y = f2bf(v.y); o.z = f2bf(v.z); o.w = f2bf(v.w);
    ((ushort4*)Xb)[i] = o;
  } else if (b < 3504) {               // W [k][n] -> Wt [n][k] bf16, 64x64 tiles
    const int t = b - 3072;
    const int z = t / 144, rem = t % 144;
    const int k0 = (rem / 12) * 64, n0 = (rem % 12) * 64;
    const float* W = (z == 0) ? Wq : (z == 1) ? Wk : Wv;
    unsigned short* Od = Wt + (size_t)z * HID * HID;
    #pragma unroll
    for (int i = tid; i < 512; i += 256) {
      const int kr = i >> 3, c8 = (i & 7) * 8;
      const float4 a = *(const float4*)&W[(size_t)(k0 + kr) * HID + n0 + c8];
      const float4 bb = *(const float4*)&W[(size_t)(k0 + kr) * HID + n0 + c8 + 4];
      T[kr][c8 + 0] = f2bf(a.x);  T[kr][c8 + 1] = f2bf(a.y);
      T[kr][c8 + 2] = f2bf(a.z);  T[kr][c8 + 3] = f2bf(a.w);
      T[kr][c8 + 4] = f2bf(bb.x); T[kr][c8 + 5] = f2bf(bb.y);
      T[kr][c8 + 6] = f2bf(bb.z); T[kr][c8 + 7] = f2bf(bb.w);
    }
    __syncthreads();
    #pragma unroll
    for (int i = tid; i < 512; i += 256) {
      const int nr = i >> 3, c8 = (i & 7) * 8;
      ushort4 lo, hi;
      lo.x = T[c8 + 0][nr]; lo.y = T[c8 + 1][nr]; lo.z = T[c8 + 2][nr]; lo.w = T[c8 + 3][nr];
      hi.x = T[c8 + 4][nr]; hi.y = T[c8 + 5][nr]; hi.z = T[c8 + 6][nr]; hi.w = T[c8 + 7][nr];
      ushort4* dst = (ushort4*)&Od[(size_t)(n0 + nr) * HID + k0 + c8];
      dst[0] = lo; dst[1] = hi;
    }
  } else if (b < 6576) {               // zero O
    ((float4*)O)[(b - 3504) * 256 + tid] = (float4){0.f, 0.f, 0.f, 0.f};
  } else {                             // zero L
    ((float4*)L)[(b - 6576) * 256 + tid] = (float4){0.f, 0.f, 0.f, 0.f};
  }
}

// ---------------------------------------------------------------------------
// Kernel 1: QKV projection, split-z, double-buffered LDS (ONE barrier/iter).
// 64x64 tile, BK=64, register prefetch distance 2, XOR-swizzled LDS,
// LDS-restaged coalesced epilogue. Q pre-scaled by 0.125*log2(e).
// V written [h][d][s_p]: within each 32-key block, key kappa stored at
// p(kappa) = ((kappa>>2)&3)*8 + (kappa&3) + ((kappa&16)?4:0)
// (= the 16x16x32 MFMA A-fragment key order of attn's concatenated P pairs).
// ---------------------------------------------------------------------------
__global__ __launch_bounds__(256) void qkv_proj(
    const unsigned short* __restrict__ Xb, const unsigned short* __restrict__ Wt,
    const float* __restrict__ bq, const float* __restrict__ bk, const float* __restrict__ bv,
    unsigned short* __restrict__ Qo, unsigned short* __restrict__ Ko, unsigned short* __restrict__ Vo)
{
  const int z = blockIdx.z;
  const unsigned short* W = Wt + (size_t)z * HID * HID;   // [n][k]
  const float* bias = (z == 0) ? bq : (z == 1) ? bk : bv;
  unsigned short* Out = (z == 0) ? Qo : (z == 1) ? Ko : Vo;

  const int tid  = threadIdx.x;
  const int wave = tid >> 6;
  const int lane = tid & 63;
  const int g = lane >> 4, c = lane & 15;
  const int h  = blockIdx.x;
  const int n0 = h * 64;
  const int m0 = blockIdx.y * 64;

  __shared__ unsigned short XB[2][4096];
  __shared__ unsigned short WB[2][4096];

  const int r0 = tid >> 3, c80 = (tid & 7) * 8;
  const unsigned sOff0 = r0 * 64 + (c80 ^ ((r0 & 7) * 8));
  const unsigned sOff1 = (r0 + 32) * 64 + (c80 ^ ((r0 & 7) * 8));
  const unsigned short* xS0 = &Xb[(size_t)(m0 + r0) * HID + c80];
  const unsigned short* xS1 = &Xb[(size_t)(m0 + r0 + 32) * HID + c80];
  const unsigned short* wS0 = &W[(size_t)(n0 + r0) * HID + c80];
  const unsigned short* wS1 = &W[(size_t)(n0 + r0 + 32) * HID + c80];

  // tile 0 -> buf 0, then prefetch tile 1 into regs
  {
    const bf16x8 a = *(const bf16x8*)xS0, b = *(const bf16x8*)xS1;
    const bf16x8 d = *(const bf16x8*)wS0, e = *(const bf16x8*)wS1;
    *(bf16x8*)&XB[0][sOff0] = a; *(bf16x8*)&XB[0][sOff1] = b;
    *(bf16x8*)&WB[0][sOff0] = d; *(bf16x8*)&WB[0][sOff1] = e;
  }
  xS0 += 64; xS1 += 64; wS0 += 64; wS1 += 64;
  bf16x8 rx0 = *(const bf16x8*)xS0, rx1 = *(const bf16x8*)xS1;
  bf16x8 rw0 = *(const bf16x8*)wS0, rw1 = *(const bf16x8*)wS1;

  const int swz = (c & 7) * 8;
  unsigned aRi[2], bRi[8];
  aRi[0] = (wave * 16 + c) * 64 + ((g * 8) ^ swz);
  aRi[1] = (wave * 16 + c) * 64 + ((32 + g * 8) ^ swz);
  #pragma unroll
  for (int nt = 0; nt < 4; ++nt) {
    bRi[2 * nt]     = (nt * 16 + c) * 64 + ((g * 8) ^ swz);
    bRi[2 * nt + 1] = (nt * 16 + c) * 64 + ((32 + g * 8) ^ swz);
  }

  f32x4 acc[4] = {{0.f,0.f,0.f,0.f},{0.f,0.f,0.f,0.f},{0.f,0.f,0.f,0.f},{0.f,0.f,0.f,0.f}};

  for (int i = 0; i < 12; ++i) {
    __syncthreads();                        // buf[i&1] staged; buf[(i+1)&1] reads done
    const int cur = i & 1;
    if (i + 1 < 12) {
      const int nxt = cur ^ 1;
      *(bf16x8*)&XB[nxt][sOff0] = rx0; *(bf16x8*)&XB[nxt][sOff1] = rx1;
      *(bf16x8*)&WB[nxt][sOff0] = rw0; *(bf16x8*)&WB[nxt][sOff1] = rw1;
      if (i + 2 < 12) {
        xS0 += 64; xS1 += 64; wS0 += 64; wS1 += 64;
        rx0 = *(const bf16x8*)xS0; rx1 = *(const bf16x8*)xS1;
        rw0 = *(const bf16x8*)wS0; rw1 = *(const bf16x8*)wS1;
      }
    }
    const unsigned short* Xl = XB[cur];
    const unsigned short* Wl = WB[cur];
    const bf16x8 a0 = *(const bf16x8*)&Xl[aRi[0]];
    const bf16x8 a1 = *(const bf16x8*)&Xl[aRi[1]];
    #pragma unroll
    for (int nt = 0; nt < 4; ++nt) {
      const bf16x8 b0 = *(const bf16x8*)&Wl[bRi[2 * nt]];
      const bf16x8 b1 = *(const bf16x8*)&Wl[bRi[2 * nt + 1]];
      acc[nt] = __builtin_amdgcn_mfma_f32_16x16x32_bf16(a0, b0, acc[nt], 0, 0, 0);
      acc[nt] = __builtin_amdgcn_mfma_f32_16x16x32_bf16(a1, b1, acc[nt], 0, 0, 0);
    }
  }

  // epilogue: restage through XB[0] (swizzled) -> coalesced b128 stores
  const float qsc = (z == 0) ? 0.1803368782f : 1.0f;   // 0.125 * log2(e)
  __syncthreads();
  unsigned short* Sm = XB[0];
  #pragma unroll
  for (int nt = 0; nt < 4; ++nt) {
    const float bv_ = bias[n0 + nt * 16 + c];
    #pragma unroll
    for (int r = 0; r < 4; ++r) {
      const unsigned short val = f2bf((acc[nt][r] + bv_) * qsc);
      if (z == 2) {
        // V: row=d, col = p(s_local): s_local = wave*16+4g+r ->
        // col = (wave>>1)*32 + g*8 + r + (wave&1)*4
        const int row = nt * 16 + c;
        const int col = (wave >> 1) * 32 + g * 8 + r + (wave & 1) * 4;
        Sm[row * 64 + (col ^ ((row & 7) * 8))] = val;
      } else {
        const int row = wave * 16 + 4 * g + r;
        const int col = nt * 16 + c;
        Sm[row * 64 + (col ^ ((row & 7) * 8))] = val;
      }
    }
  }
  __syncthreads();
  #pragma unroll
  for (int jj = 0; jj < 2; ++jj) {
    const int j = tid + 256 * jj, row = j >> 3, c8 = (j & 7) * 8;
    const bf16x8 v = *(const bf16x8*)&Sm[row * 64 + (c8 ^ ((row & 7) * 8))];
    if (z == 2)
      *(bf16x8*)&Out[((size_t)h * HD + row) * S_LEN + m0 + c8] = v;   // [h][d][s_p]
    else
      *(bf16x8*)&Out[((size_t)h * S_LEN + m0 + row) * HD + c8] = v;   // [h][s][d]
  }
}

// ---------------------------------------------------------------------------
// Kernel 2: attention. 4 waves x 32 q = 128 q/WG, KV-split 4 -> 1536 WGs.
// Double-buffered K/V LDS (ONE barrier/iter, 32 KB). S^T = K Q^T (16x16x32);
// exp2 + truncating v_perm pack in registers; concatenated P pairs feed PV as
// 16x16x32 A-fragments against key-permuted V (b128 B-frags). Denominator via
// ones-column MFMA. Partials atomicAdd'ed (4 contributions per element).
// ---------------------------------------------------------------------------
__global__ __launch_bounds__(256, 4) void attn(
    const unsigned short* __restrict__ Q, const unsigned short* __restrict__ K,
    const unsigned short* __restrict__ Vp,   // [h][d][s_p]
    float* __restrict__ O, float* __restrict__ L)
{
  const int qt = blockIdx.x;   // 0..31
  const int h  = blockIdx.y;   // 0..11
  const int sp = blockIdx.z;   // 0..3
  const int tid  = threadIdx.x;
  const int wave = tid >> 6;
  const int lane = tid & 63;
  const int g = lane >> 4, c = lane & 15;
  const int q0 = qt * 128;
  const int k_base = sp * 1024;
  const int NIT = 16;

  __shared__ unsigned short KB[2][4096];   // [key][d] swizzled
  __shared__ unsigned short VB[2][4096];   // [d][key_p] swizzled

  // Q B-frags (loop-invariant, from global)
  bf16x8 aq[2][2];
  #pragma unroll
  for (int s = 0; s < 2; ++s) {
    const size_t qrow = (size_t)h * S_LEN + q0 + wave * 32 + s * 16 + c;
    aq[s][0] = *(const bf16x8*)&Q[qrow * HD + g * 8];
    aq[s][1] = *(const bf16x8*)&Q[qrow * HD + 32 + g * 8];
  }

  bf16x8 bones8;   // B column 0 = 1.0 for all k -> C[:,0] = row sums
  {
    const unsigned short one_bf = (c == 0) ? 0x3F80u : 0u;
    #pragma unroll
    for (int j = 0; j < 8; ++j) ((unsigned short*)&bones8)[j] = one_bf;
  }

  const int swz = (c & 7) * 8;
  unsigned kRi[8], vRi[8];
  #pragma unroll
  for (int mt = 0; mt < 4; ++mt) {
    kRi[2 * mt]     = (mt * 16 + c) * 64 + ((g * 8) ^ swz);
    kRi[2 * mt + 1] = (mt * 16 + c) * 64 + ((32 + g * 8) ^ swz);
  }
  #pragma unroll
  for (int dt = 0; dt < 4; ++dt) {
    vRi[2 * dt]     = (dt * 16 + c) * 64 + ((g * 8) ^ swz);
    vRi[2 * dt + 1] = (dt * 16 + c) * 64 + ((32 + g * 8) ^ swz);
  }

  // staging: LDS offsets invariant; global pointers advance
  const int r0 = tid >> 3, c80 = (tid & 7) * 8;
  const unsigned sOff0 = r0 * 64 + (c80 ^ ((r0 & 7) * 8));
  const unsigned sOff1 = (r0 + 32) * 64 + (c80 ^ ((r0 & 7) * 8));
  const unsigned short* kS0 = &K[((size_t)h * S_LEN + k_base + r0) * HD + c80];
  const unsigned short* kS1 = kS0 + (size_t)32 * HD;
  const unsigned short* vS0 = &Vp[((size_t)h * HD + r0) * S_LEN + k_base + c80];
  const unsigned short* vS1 = vS0 + (size_t)32 * S_LEN;

  // tile 0 -> buf 0; prefetch tile 1 into regs
  {
    const bf16x8 a = *(const bf16x8*)kS0, b = *(const bf16x8*)kS1;
    const bf16x8 d = *(const bf16x8*)vS0, e = *(const bf16x8*)vS1;
    *(bf16x8*)&KB[0][sOff0] = a; *(bf16x8*)&KB[0][sOff1] = b;
    *(bf16x8*)&VB[0][sOff0] = d; *(bf16x8*)&VB[0][sOff1] = e;
  }
  kS0 += 64 * HD; kS1 += 64 * HD; vS0 += 64; vS1 += 64;
  bf16x8 rk0 = *(const bf16x8*)kS0, rk1 = *(const bf16x8*)kS1;
  bf16x8 rv0 = *(const bf16x8*)vS0, rv1 = *(const bf16x8*)vS1;

  f32x4 o[2][4];
  #pragma unroll
  for (int s = 0; s < 2; ++s)
    #pragma unroll
    for (int dt = 0; dt < 4; ++dt) o[s][dt] = (f32x4){0.f, 0.f, 0.f, 0.f};
  f32x4 lacc[2] = {{0.f,0.f,0.f,0.f},{0.f,0.f,0.f,0.f}};

  for (int kt = 0; kt < NIT; ++kt) {
    __syncthreads();                 // buf[kt&1] staged; buf[(kt+1)&1] reads done
    const int cur = kt & 1;
    if (kt + 1 < NIT) {
      const int nxt = cur ^ 1;
      *(bf16x8*)&KB[nxt][sOff0] = rk0; *(bf16x8*)&KB[nxt][sOff1] = rk1;
      *(bf16x8*)&VB[nxt][sOff0] = rv0; *(bf16x8*)&VB[nxt][sOff1] = rv1;
      if (kt + 2 < NIT) {
        kS0 += 64 * HD; kS1 += 64 * HD; vS0 += 64; vS1 += 64;
        rk0 = *(const bf16x8*)kS0; rk1 = *(const bf16x8*)kS1;
        rv0 = *(const bf16x8*)vS0; rv1 = *(const bf16x8*)vS1;
      }
    }
    const unsigned short* Kl = KB[cur];
    const unsigned short* Vt = VB[cur];

    // S^T = K Q^T per 16-key tile; exp2 + pack; concat pairs -> x32 A-frags.
    // apack[s][t] element j: j<4 -> P[q=c][32t+4g+j], j>=4 -> P[q=c][32t+16+4g+j-4]
    bf16x8 apack[2][2];
    #pragma unroll
    for (int t = 0; t < 2; ++t) {
      const bf16x8 kf00 = *(const bf16x8*)&Kl[kRi[4 * t + 0]];
      const bf16x8 kf01 = *(const bf16x8*)&Kl[kRi[4 * t + 1]];
      const bf16x8 kf10 = *(const bf16x8*)&Kl[kRi[4 * t + 2]];
      const bf16x8 kf11 = *(const bf16x8*)&Kl[kRi[4 * t + 3]];
      #pragma unroll
      for (int s = 0; s < 2; ++s) {
        f32x4 sa = {0.f,0.f,0.f,0.f}, sb = {0.f,0.f,0.f,0.f};
        sa = __builtin_amdgcn_mfma_f32_16x16x32_bf16(kf00, aq[s][0], sa, 0, 0, 0);
        sa = __builtin_amdgcn_mfma_f32_16x16x32_bf16(kf01, aq[s][1], sa, 0, 0, 0);
        sb = __builtin_amdgcn_mfma_f32_16x16x32_bf16(kf10, aq[s][0], sb, 0, 0, 0);
        sb = __builtin_amdgcn_mfma_f32_16x16x32_bf16(kf11, aq[s][1], sb, 0, 0, 0);
        union { unsigned u[4]; bf16x8 v; } pk;
        pk.u[0] = pktr(__builtin_amdgcn_exp2f(sa[0]), __builtin_amdgcn_exp2f(sa[1]));
        pk.u[1] = pktr(__builtin_amdgcn_exp2f(sa[2]), __builtin_amdgcn_exp2f(sa[3]));
        pk.u[2] = pktr(__builtin_amdgcn_exp2f(sb[0]), __builtin_amdgcn_exp2f(sb[1]));
        pk.u[3] = pktr(__builtin_amdgcn_exp2f(sb[2]), __builtin_amdgcn_exp2f(sb[3]));
        apack[s][t] = pk.v;
      }
    }

    // O += P V  (x32 MFMAs; V b128 B-frags in matching key-permuted order)
    #pragma unroll
    for (int dt = 0; dt < 4; ++dt) {
      const bf16x8 vb0 = *(const bf16x8*)&Vt[vRi[2 * dt]];
      const bf16x8 vb1 = *(const bf16x8*)&Vt[vRi[2 * dt + 1]];
      #pragma unroll
      for (int s = 0; s < 2; ++s) {
        o[s][dt] = __builtin_amdgcn_mfma_f32_16x16x32_bf16(apack[s][0], vb0, o[s][dt], 0, 0, 0);
        o[s][dt] = __builtin_amdgcn_mfma_f32_16x16x32_bf16(apack[s][1], vb1, o[s][dt], 0, 0, 0);
      }
    }
    #pragma unroll
    for (int s = 0; s < 2; ++s) {
      lacc[s] = __builtin_amdgcn_mfma_f32_16x16x32_bf16(apack[s][0], bones8, lacc[s], 0, 0, 0);
      lacc[s] = __builtin_amdgcn_mfma_f32_16x16x32_bf16(apack[s][1], bones8, lacc[s], 0, 0, 0);
    }
  }

  // epilogue: accumulate partials (exactly 4 contributions per element)
  #pragma unroll
  for (int s = 0; s < 2; ++s) {
    #pragma unroll
    for (int dt = 0; dt < 4; ++dt) {
      #pragma unroll
      for (int r = 0; r < 4; ++r) {
        const int row = q0 + wave * 32 + s * 16 + 4 * g + r;
        atomicAdd(&O[(size_t)row * HID + h * HD + dt * 16 + c], o[s][dt][r]);
      }
    }
  }
  if (c == 0) {
    #pragma unroll
    for (int s = 0; s < 2; ++s)
      #pragma unroll
      for (int r = 0; r < 4; ++r)
        atomicAdd(&L[h * S_LEN + q0 + wave * 32 + s * 16 + 4 * g + r], lacc[s][r]);
  }
}

// ---------------------------------------------------------------------------
// Kernel 3: normalize O by softmax denominator
// ---------------------------------------------------------------------------
__global__ __launch_bounds__(256) void normalize(float* __restrict__ O,
                                                 const float* __restrict__ L)
{
  const int i = blockIdx.x * 256 + threadIdx.x;
  float4 v = ((const float4*)O)[i];
  const int idx4 = i * 4;
  const int row = idx4 / HID;
  const int h   = (idx4 % HID) >> 6;
  const float inv = 1.0f / L[h * S_LEN + row];
  v.x *= inv; v.y *= inv; v.z *= inv; v.w *= inv;
  ((float4*)O)[i] = v;
}

// ---------------------------------------------------------------------------
extern "C" void kernel_launch(void* const* d_in, const int* in_sizes, int n_in,
                              void* d_out, int out_size, void* d_ws, size_t ws_size,
                              hipStream_t stream) {
  const float* X  = (const float*)d_in[0];
  const float* Wq = (const float*)d_in[1];
  const float* bq = (const float*)d_in[2];
  const float* Wk = (const float*)d_in[3];
  const float* bk = (const float*)d_in[4];
  const float* Wv = (const float*)d_in[5];
  const float* bv = (const float*)d_in[6];

  unsigned short* Xb = (unsigned short*)d_ws;
  unsigned short* Wt = Xb + (size_t)S_LEN * HID;
  unsigned short* Qb = Wt + (size_t)3 * HID * HID;
  unsigned short* Kb = Qb + (size_t)NH * S_LEN * HD;
  unsigned short* Vb = Kb + (size_t)NH * S_LEN * HD;
  float* L = (float*)(Vb + (size_t)NH * S_LEN * HD);
  float* O = (float*)d_out;

  prep<<<dim3(6624), 256, 0, stream>>>(X, Wq, Wk, Wv, Xb, Wt, O, L);
  qkv_proj<<<dim3(12, 64, 3), 256, 0, stream>>>(Xb, Wt, bq, bk, bv, Qb, Kb, Vb);
  attn<<<dim3(32, 12, 4), 256, 0, stream>>>(Qb, Kb, Vb, O, L);
  normalize<<<dim3((S_LEN * HID / 4) / 256), 256, 0, stream>>>(O, L);
}

// Round 10
// 184.541 us; speedup vs baseline: 1.2115x; 1.0056x over previous
//
#include <hip/hip_runtime.h>
#include <hip/hip_bf16.h>

#define S_LEN 4096
#define HID   768
#define NH    12
#define HD    64

typedef __attribute__((ext_vector_type(8))) __bf16 bf16x8;
typedef __attribute__((ext_vector_type(4))) float  f32x4;

// round-to-nearest-even fp32 -> bf16
__device__ __forceinline__ unsigned short f2bf(float f) {
  union { float f; unsigned u; } v; v.f = f;
  unsigned r = v.u + 0x7fffu + ((v.u >> 16) & 1u);
  return (unsigned short)(r >> 16);
}

// truncating pack of two fp32 into [bf16(hi) | bf16(lo)] — single v_perm_b32.
// Truncation bias cancels in O = (P V)/(P 1) since denominator uses same P.
__device__ __forceinline__ unsigned pktr(float lo, float hi) {
  union { float f; unsigned u; } a, b; a.f = lo; b.f = hi;
  return __builtin_amdgcn_perm(b.u, a.u, 0x07060302u);
}

// ---------------------------------------------------------------------------
// Prep (single launch): X->bf16 | W->Wt bf16 transposed | zero O | zero L
// ---------------------------------------------------------------------------
__global__ __launch_bounds__(256) void prep(
    const float* __restrict__ X,
    const float* __restrict__ Wq, const float* __restrict__ Wk, const float* __restrict__ Wv,
    unsigned short* __restrict__ Xb, unsigned short* __restrict__ Wt,
    float* __restrict__ O, float* __restrict__ L)
{
  const int b = blockIdx.x, tid = threadIdx.x;
  __shared__ unsigned short T[64][72];

  if (b < 3072) {                      // X fp32 -> bf16
    const int i = b * 256 + tid;
    const float4 v = ((const float4*)X)[i];
    ushort4 o;
    o.x = f2bf(v.x); o.y = f2bf(v.y); o.z = f2bf(v.z); o.w = f2bf(v.w);
    ((ushort4*)Xb)[i] = o;
  } else if (b < 3504) {               // W [k][n] -> Wt [n][k] bf16, 64x64 tiles
    const int t = b - 3072;
    const int z = t / 144, rem = t % 144;
    const int k0 = (rem / 12) * 64, n0 = (rem % 12) * 64;
    const float* W = (z == 0) ? Wq : (z == 1) ? Wk : Wv;
    unsigned short* Od = Wt + (size_t)z * HID * HID;
    #pragma unroll
    for (int i = tid; i < 512; i += 256) {
      const int kr = i >> 3, c8 = (i & 7) * 8;
      const float4 a = *(const float4*)&W[(size_t)(k0 + kr) * HID + n0 + c8];
      const float4 bb = *(const float4*)&W[(size_t)(k0 + kr) * HID + n0 + c8 + 4];
      T[kr][c8 + 0] = f2bf(a.x);  T[kr][c8 + 1] = f2bf(a.y);
      T[kr][c8 + 2] = f2bf(a.z);  T[kr][c8 + 3] = f2bf(a.w);
      T[kr][c8 + 4] = f2bf(bb.x); T[kr][c8 + 5] = f2bf(bb.y);
      T[kr][c8 + 6] = f2bf(bb.z); T[kr][c8 + 7] = f2bf(bb.w);
    }
    __syncthreads();
    #pragma unroll
    for (int i = tid; i < 512; i += 256) {
      const int nr = i >> 3, c8 = (i & 7) * 8;
      ushort4 lo, hi;
      lo.x = T[c8 + 0][nr]; lo.y = T[c8 + 1][nr]; lo.z = T[c8 + 2][nr]; lo.w = T[c8 + 3][nr];
      hi.x = T[c8 + 4][nr]; hi.y = T[c8 + 5][nr]; hi.z = T[c8 + 6][nr]; hi.w = T[c8 + 7][nr];
      ushort4* dst = (ushort4*)&Od[(size_t)(n0 + nr) * HID + k0 + c8];
      dst[0] = lo; dst[1] = hi;
    }
  } else if (b < 6576) {               // zero O
    ((float4*)O)[(b - 3504) * 256 + tid] = (float4){0.f, 0.f, 0.f, 0.f};
  } else {                             // zero L
    ((float4*)L)[(b - 6576) * 256 + tid] = (float4){0.f, 0.f, 0.f, 0.f};
  }
}

// ---------------------------------------------------------------------------
// Kernel 1: QKV projection, split-z, SINGLE-buffered 16 KB LDS (residency:
// 2304 WGs, ~9/CU — measured better than 32 KB dbuf variant). 64x64 tile,
// BK=64, register prefetch, XOR-swizzled LDS, LDS-restaged coalesced
// epilogue. Q pre-scaled by 0.125*log2(e). V written [h][d][s_p] with
// within-32-block key permutation p(k) = ((k>>2)&3)*8 + (k&3) + ((k&16)?4:0)
// (= attn's concatenated-P A-fragment key order).
// ---------------------------------------------------------------------------
__global__ __launch_bounds__(256) void qkv_proj(
    const unsigned short* __restrict__ Xb, const unsigned short* __restrict__ Wt,
    const float* __restrict__ bq, const float* __restrict__ bk, const float* __restrict__ bv,
    unsigned short* __restrict__ Qo, unsigned short* __restrict__ Ko, unsigned short* __restrict__ Vo)
{
  const int z = blockIdx.z;
  const unsigned short* W = Wt + (size_t)z * HID * HID;   // [n][k]
  const float* bias = (z == 0) ? bq : (z == 1) ? bk : bv;
  unsigned short* Out = (z == 0) ? Qo : (z == 1) ? Ko : Vo;

  const int tid  = threadIdx.x;
  const int wave = tid >> 6;
  const int lane = tid & 63;
  const int g = lane >> 4, c = lane & 15;
  const int h  = blockIdx.x;
  const int n0 = h * 64;
  const int m0 = blockIdx.y * 64;

  __shared__ unsigned short Xl[4096];   // [m][k] swizzled
  __shared__ unsigned short Wl[4096];   // [n][k] swizzled

  const int r0 = tid >> 3, c80 = (tid & 7) * 8;
  const unsigned sOff0 = r0 * 64 + (c80 ^ ((r0 & 7) * 8));
  const unsigned sOff1 = (r0 + 32) * 64 + (c80 ^ ((r0 & 7) * 8));
  const unsigned short* xS0 = &Xb[(size_t)(m0 + r0) * HID + c80];
  const unsigned short* xS1 = &Xb[(size_t)(m0 + r0 + 32) * HID + c80];
  const unsigned short* wS0 = &W[(size_t)(n0 + r0) * HID + c80];
  const unsigned short* wS1 = &W[(size_t)(n0 + r0 + 32) * HID + c80];

  bf16x8 rx0 = *(const bf16x8*)xS0, rx1 = *(const bf16x8*)xS1;
  bf16x8 rw0 = *(const bf16x8*)wS0, rw1 = *(const bf16x8*)wS1;

  const int swz = (c & 7) * 8;
  unsigned aRi[2], bRi[8];
  aRi[0] = (wave * 16 + c) * 64 + ((g * 8) ^ swz);
  aRi[1] = (wave * 16 + c) * 64 + ((32 + g * 8) ^ swz);
  #pragma unroll
  for (int nt = 0; nt < 4; ++nt) {
    bRi[2 * nt]     = (nt * 16 + c) * 64 + ((g * 8) ^ swz);
    bRi[2 * nt + 1] = (nt * 16 + c) * 64 + ((32 + g * 8) ^ swz);
  }

  f32x4 acc[4] = {{0.f,0.f,0.f,0.f},{0.f,0.f,0.f,0.f},{0.f,0.f,0.f,0.f},{0.f,0.f,0.f,0.f}};

  for (int k0 = 0; k0 < HID; k0 += 64) {
    __syncthreads();
    *(bf16x8*)&Xl[sOff0] = rx0;
    *(bf16x8*)&Xl[sOff1] = rx1;
    *(bf16x8*)&Wl[sOff0] = rw0;
    *(bf16x8*)&Wl[sOff1] = rw1;
    __syncthreads();

    if (k0 + 64 < HID) {   // prefetch next k-slab (lands during MFMAs)
      xS0 += 64; xS1 += 64; wS0 += 64; wS1 += 64;
      rx0 = *(const bf16x8*)xS0; rx1 = *(const bf16x8*)xS1;
      rw0 = *(const bf16x8*)wS0; rw1 = *(const bf16x8*)wS1;
    }

    const bf16x8 a0 = *(const bf16x8*)&Xl[aRi[0]];
    const bf16x8 a1 = *(const bf16x8*)&Xl[aRi[1]];
    #pragma unroll
    for (int nt = 0; nt < 4; ++nt) {
      const bf16x8 b0 = *(const bf16x8*)&Wl[bRi[2 * nt]];
      const bf16x8 b1 = *(const bf16x8*)&Wl[bRi[2 * nt + 1]];
      acc[nt] = __builtin_amdgcn_mfma_f32_16x16x32_bf16(a0, b0, acc[nt], 0, 0, 0);
      acc[nt] = __builtin_amdgcn_mfma_f32_16x16x32_bf16(a1, b1, acc[nt], 0, 0, 0);
    }
  }

  // epilogue: restage through Xl (swizzled) -> coalesced b128 stores
  const float qsc = (z == 0) ? 0.1803368782f : 1.0f;   // 0.125 * log2(e)
  __syncthreads();
  #pragma unroll
  for (int nt = 0; nt < 4; ++nt) {
    const float bv_ = bias[n0 + nt * 16 + c];
    #pragma unroll
    for (int r = 0; r < 4; ++r) {
      const unsigned short val = f2bf((acc[nt][r] + bv_) * qsc);
      if (z == 2) {
        // V: row=d, col = p(s_local); s_local = wave*16+4g+r ->
        // col = (wave>>1)*32 + g*8 + r + (wave&1)*4
        const int row = nt * 16 + c;
        const int col = (wave >> 1) * 32 + g * 8 + r + (wave & 1) * 4;
        Xl[row * 64 + (col ^ ((row & 7) * 8))] = val;
      } else {
        const int row = wave * 16 + 4 * g + r;
        const int col = nt * 16 + c;
        Xl[row * 64 + (col ^ ((row & 7) * 8))] = val;
      }
    }
  }
  __syncthreads();
  #pragma unroll
  for (int jj = 0; jj < 2; ++jj) {
    const int j = tid + 256 * jj, row = j >> 3, c8 = (j & 7) * 8;
    const bf16x8 v = *(const bf16x8*)&Xl[row * 64 + (c8 ^ ((row & 7) * 8))];
    if (z == 2)
      *(bf16x8*)&Out[((size_t)h * HD + row) * S_LEN + m0 + c8] = v;   // [h][d][s_p]
    else
      *(bf16x8*)&Out[((size_t)h * S_LEN + m0 + row) * HD + c8] = v;   // [h][s][d]
  }
}

// ---------------------------------------------------------------------------
// Kernel 2: attention (round-8, known-good). 4 waves x 32 q = 128 q/WG,
// KV-split 4 -> 1536 WGs. Double-buffered K/V LDS (ONE barrier/iter, 32 KB).
// S^T = K Q^T (16x16x32); exp2 + truncating v_perm pack in registers;
// concatenated P pairs feed PV as 16x16x32 A-fragments against key-permuted V
// (b128 B-frags). Denominator via ones-column MFMA. Partials atomicAdd'ed
// (4 contributions per element).
// ---------------------------------------------------------------------------
__global__ __launch_bounds__(256, 4) void attn(
    const unsigned short* __restrict__ Q, const unsigned short* __restrict__ K,
    const unsigned short* __restrict__ Vp,   // [h][d][s_p]
    float* __restrict__ O, float* __restrict__ L)
{
  const int qt = blockIdx.x;   // 0..31
  const int h  = blockIdx.y;   // 0..11
  const int sp = blockIdx.z;   // 0..3
  const int tid  = threadIdx.x;
  const int wave = tid >> 6;
  const int lane = tid & 63;
  const int g = lane >> 4, c = lane & 15;
  const int q0 = qt * 128;
  const int k_base = sp * 1024;
  const int NIT = 16;

  __shared__ unsigned short KB[2][4096];   // [key][d] swizzled
  __shared__ unsigned short VB[2][4096];   // [d][key_p] swizzled

  // Q B-frags (loop-invariant, from global)
  bf16x8 aq[2][2];
  #pragma unroll
  for (int s = 0; s < 2; ++s) {
    const size_t qrow = (size_t)h * S_LEN + q0 + wave * 32 + s * 16 + c;
    aq[s][0] = *(const bf16x8*)&Q[qrow * HD + g * 8];
    aq[s][1] = *(const bf16x8*)&Q[qrow * HD + 32 + g * 8];
  }

  bf16x8 bones8;   // B column 0 = 1.0 -> C[:,0] = row sums
  {
    const unsigned short one_bf = (c == 0) ? 0x3F80u : 0u;
    #pragma unroll
    for (int j = 0; j < 8; ++j) ((unsigned short*)&bones8)[j] = one_bf;
  }

  const int swz = (c & 7) * 8;
  unsigned kRi[8], vRi[8];
  #pragma unroll
  for (int mt = 0; mt < 4; ++mt) {
    kRi[2 * mt]     = (mt * 16 + c) * 64 + ((g * 8) ^ swz);
    kRi[2 * mt + 1] = (mt * 16 + c) * 64 + ((32 + g * 8) ^ swz);
    vRi[2 * mt]     = kRi[2 * mt];
    vRi[2 * mt + 1] = kRi[2 * mt + 1];
  }

  const int r0 = tid >> 3, c80 = (tid & 7) * 8;
  const unsigned sOff0 = r0 * 64 + (c80 ^ ((r0 & 7) * 8));
  const unsigned sOff1 = (r0 + 32) * 64 + (c80 ^ ((r0 & 7) * 8));
  const unsigned short* kS0 = &K[((size_t)h * S_LEN + k_base + r0) * HD + c80];
  const unsigned short* kS1 = kS0 + (size_t)32 * HD;
  const unsigned short* vS0 = &Vp[((size_t)h * HD + r0) * S_LEN + k_base + c80];
  const unsigned short* vS1 = vS0 + (size_t)32 * S_LEN;

  {
    const bf16x8 a = *(const bf16x8*)kS0, b = *(const bf16x8*)kS1;
    const bf16x8 d = *(const bf16x8*)vS0, e = *(const bf16x8*)vS1;
    *(bf16x8*)&KB[0][sOff0] = a; *(bf16x8*)&KB[0][sOff1] = b;
    *(bf16x8*)&VB[0][sOff0] = d; *(bf16x8*)&VB[0][sOff1] = e;
  }
  kS0 += 64 * HD; kS1 += 64 * HD; vS0 += 64; vS1 += 64;
  bf16x8 rk0 = *(const bf16x8*)kS0, rk1 = *(const bf16x8*)kS1;
  bf16x8 rv0 = *(const bf16x8*)vS0, rv1 = *(const bf16x8*)vS1;

  f32x4 o[2][4];
  #pragma unroll
  for (int s = 0; s < 2; ++s)
    #pragma unroll
    for (int dt = 0; dt < 4; ++dt) o[s][dt] = (f32x4){0.f, 0.f, 0.f, 0.f};
  f32x4 lacc[2] = {{0.f,0.f,0.f,0.f},{0.f,0.f,0.f,0.f}};

  for (int kt = 0; kt < NIT; ++kt) {
    __syncthreads();                 // buf[kt&1] staged; buf[(kt+1)&1] reads done
    const int cur = kt & 1;
    if (kt + 1 < NIT) {
      const int nxt = cur ^ 1;
      *(bf16x8*)&KB[nxt][sOff0] = rk0; *(bf16x8*)&KB[nxt][sOff1] = rk1;
      *(bf16x8*)&VB[nxt][sOff0] = rv0; *(bf16x8*)&VB[nxt][sOff1] = rv1;
      if (kt + 2 < NIT) {
        kS0 += 64 * HD; kS1 += 64 * HD; vS0 += 64; vS1 += 64;
        rk0 = *(const bf16x8*)kS0; rk1 = *(const bf16x8*)kS1;
        rv0 = *(const bf16x8*)vS0; rv1 = *(const bf16x8*)vS1;
      }
    }
    const unsigned short* Kl = KB[cur];
    const unsigned short* Vt = VB[cur];

    // S^T = K Q^T per 16-key tile; exp2 + pack; concat pairs -> x32 A-frags
    bf16x8 apack[2][2];
    #pragma unroll
    for (int t = 0; t < 2; ++t) {
      const bf16x8 kf00 = *(const bf16x8*)&Kl[kRi[4 * t + 0]];
      const bf16x8 kf01 = *(const bf16x8*)&Kl[kRi[4 * t + 1]];
      const bf16x8 kf10 = *(const bf16x8*)&Kl[kRi[4 * t + 2]];
      const bf16x8 kf11 = *(const bf16x8*)&Kl[kRi[4 * t + 3]];
      #pragma unroll
      for (int s = 0; s < 2; ++s) {
        f32x4 sa = {0.f,0.f,0.f,0.f}, sb = {0.f,0.f,0.f,0.f};
        sa = __builtin_amdgcn_mfma_f32_16x16x32_bf16(kf00, aq[s][0], sa, 0, 0, 0);
        sa = __builtin_amdgcn_mfma_f32_16x16x32_bf16(kf01, aq[s][1], sa, 0, 0, 0);
        sb = __builtin_amdgcn_mfma_f32_16x16x32_bf16(kf10, aq[s][0], sb, 0, 0, 0);
        sb = __builtin_amdgcn_mfma_f32_16x16x32_bf16(kf11, aq[s][1], sb, 0, 0, 0);
        union { unsigned u[4]; bf16x8 v; } pk;
        pk.u[0] = pktr(__builtin_amdgcn_exp2f(sa[0]), __builtin_amdgcn_exp2f(sa[1]));
        pk.u[1] = pktr(__builtin_amdgcn_exp2f(sa[2]), __builtin_amdgcn_exp2f(sa[3]));
        pk.u[2] = pktr(__builtin_amdgcn_exp2f(sb[0]), __builtin_amdgcn_exp2f(sb[1]));
        pk.u[3] = pktr(__builtin_amdgcn_exp2f(sb[2]), __builtin_amdgcn_exp2f(sb[3]));
        apack[s][t] = pk.v;
      }
    }

    #pragma unroll
    for (int dt = 0; dt < 4; ++dt) {
      const bf16x8 vb0 = *(const bf16x8*)&Vt[vRi[2 * dt]];
      const bf16x8 vb1 = *(const bf16x8*)&Vt[vRi[2 * dt + 1]];
      #pragma unroll
      for (int s = 0; s < 2; ++s) {
        o[s][dt] = __builtin_amdgcn_mfma_f32_16x16x32_bf16(apack[s][0], vb0, o[s][dt], 0, 0, 0);
        o[s][dt] = __builtin_amdgcn_mfma_f32_16x16x32_bf16(apack[s][1], vb1, o[s][dt], 0, 0, 0);
      }
    }
    #pragma unroll
    for (int s = 0; s < 2; ++s) {
      lacc[s] = __builtin_amdgcn_mfma_f32_16x16x32_bf16(apack[s][0], bones8, lacc[s], 0, 0, 0);
      lacc[s] = __builtin_amdgcn_mfma_f32_16x16x32_bf16(apack[s][1], bones8, lacc[s], 0, 0, 0);
    }
  }

  // epilogue: accumulate partials (exactly 4 contributions per element)
  #pragma unroll
  for (int s = 0; s < 2; ++s) {
    #pragma unroll
    for (int dt = 0; dt < 4; ++dt) {
      #pragma unroll
      for (int r = 0; r < 4; ++r) {
        const int row = q0 + wave * 32 + s * 16 + 4 * g + r;
        atomicAdd(&O[(size_t)row * HID + h * HD + dt * 16 + c], o[s][dt][r]);
      }
    }
  }
  if (c == 0) {
    #pragma unroll
    for (int s = 0; s < 2; ++s)
      #pragma unroll
      for (int r = 0; r < 4; ++r)
        atomicAdd(&L[h * S_LEN + q0 + wave * 32 + s * 16 + 4 * g + r], lacc[s][r]);
  }
}

// ---------------------------------------------------------------------------
// Kernel 3: normalize O by softmax denominator
// ---------------------------------------------------------------------------
__global__ __launch_bounds__(256) void normalize(float* __restrict__ O,
                                                 const float* __restrict__ L)
{
  const int i = blockIdx.x * 256 + threadIdx.x;
  float4 v = ((const float4*)O)[i];
  const int idx4 = i * 4;
  const int row = idx4 / HID;
  const int h   = (idx4 % HID) >> 6;
  const float inv = 1.0f / L[h * S_LEN + row];
  v.x *= inv; v.y *= inv; v.z *= inv; v.w *= inv;
  ((float4*)O)[i] = v;
}

// ---------------------------------------------------------------------------
extern "C" void kernel_launch(void* const* d_in, const int* in_sizes, int n_in,
                              void* d_out, int out_size, void* d_ws, size_t ws_size,
                              hipStream_t stream) {
  const float* X  = (const float*)d_in[0];
  const float* Wq = (const float*)d_in[1];
  const float* bq = (const float*)d_in[2];
  const float* Wk = (const float*)d_in[3];
  const float* bk = (const float*)d_in[4];
  const float* Wv = (const float*)d_in[5];
  const float* bv = (const float*)d_in[6];

  unsigned short* Xb = (unsigned short*)d_ws;
  unsigned short* Wt = Xb + (size_t)S_LEN * HID;
  unsigned short* Qb = Wt + (size_t)3 * HID * HID;
  unsigned short* Kb = Qb + (size_t)NH * S_LEN * HD;
  unsigned short* Vb = Kb + (size_t)NH * S_LEN * HD;
  float* L = (float*)(Vb + (size_t)NH * S_LEN * HD);
  float* O = (float*)d_out;

  prep<<<dim3(6624), 256, 0, stream>>>(X, Wq, Wk, Wv, Xb, Wt, O, L);
  qkv_proj<<<dim3(12, 64, 3), 256, 0, stream>>>(Xb, Wt, bq, bk, bv, Qb, Kb, Vb);
  attn<<<dim3(32, 12, 4), 256, 0, stream>>>(Qb, Kb, Vb, O, L);
  normalize<<<dim3((S_LEN * HID / 4) / 256), 256, 0, stream>>>(O, L);
}